// Round 3
// baseline (563.692 us; speedup 1.0000x reference)
//
#include <hip/hip_runtime.h>

// HubnormTripletLoss, N=8192.
// P = Sinkhorn(exp(-(1-s)/lamb), 5 iters) == P0 * R[i] * C[j] (diagonal scaling).
//   pass0 : quantize P0 -> fp8 Q (64MB), R = 1/rowsum(Q), extract diag, zero Cs0/out
//   colmv : Csum[j] += sum_rows Q[i,j]*R[i]  (atomics, ping-pong; zeroes other buf)
//   rowmv : R[i] = 1/sum_j Q[i,j]*rcp(Csum[j])   (C staged in LDS, 8 rows/block)
//   loss  : sum_{i!=j} hinge(P-d[j]) + hinge(P-d[i]),  d[k]=Qd[k]*R[k]*rcp(Csum[k])
// 11 dispatches total (was 16): colred kernels eliminated via atomic accumulation.

#define NN 8192u
#define MARGIN 0.2f
#define KF (1.4426950408889634f / 0.012f)  // log2(e)/lamb

__device__ __forceinline__ float fexp2(float x) { return __builtin_amdgcn_exp2f(x); }
__device__ __forceinline__ float frcp(float x) { return __builtin_amdgcn_rcpf(x); }

__device__ __forceinline__ void unpk4(uint q, float& f0, float& f1, float& f2,
                                      float& f3) {
  auto lo = __builtin_amdgcn_cvt_pk_f32_fp8((int)q, false);
  auto hi = __builtin_amdgcn_cvt_pk_f32_fp8((int)q, true);
  f0 = lo[0]; f1 = lo[1]; f2 = hi[0]; f3 = hi[1];
}

__device__ __forceinline__ float blk_reduce(float v, float* red) {
#pragma unroll
  for (int off = 32; off; off >>= 1) v += __shfl_down(v, off, 64);
  const int lane = threadIdx.x & 63, wid = threadIdx.x >> 6;
  __syncthreads();  // protect red[] reuse across calls
  if (lane == 0) red[wid] = v;
  __syncthreads();
  return red[0] + red[1] + red[2] + red[3];
}

// ---- pass0: quantize, rowsum -> R, diag -> Qd, zero Cs0 and out -------------
__global__ __launch_bounds__(256) void k_pass0(const float* __restrict__ sims,
                                               uint* __restrict__ Qw,
                                               float* __restrict__ R,
                                               float* __restrict__ Qd,
                                               float* __restrict__ Cs0,
                                               float* __restrict__ out) {
  __shared__ float red[4];
  const uint row = blockIdx.x;
  const uint t = threadIdx.x;
  float acc = 0.f;
#pragma unroll
  for (uint ch = 0; ch < 8; ++ch) {
    const uint col = ch * 1024u + t * 4u;
    const float4 s = *(const float4*)(sims + (size_t)row * NN + col);
    const float p0 = fexp2((s.x - 1.f) * KF);
    const float p1 = fexp2((s.y - 1.f) * KF);
    const float p2 = fexp2((s.z - 1.f) * KF);
    const float p3 = fexp2((s.w - 1.f) * KF);
    int pk = 0;
    pk = __builtin_amdgcn_cvt_pk_fp8_f32(p0, p1, pk, false);
    pk = __builtin_amdgcn_cvt_pk_fp8_f32(p2, p3, pk, true);
    Qw[((size_t)row * NN + col) >> 2] = (uint)pk;
    // sum QUANTIZED values so later passes are self-consistent
    float q0, q1, q2, q3;
    unpk4((uint)pk, q0, q1, q2, q3);
    acc += (q0 + q1) + (q2 + q3);
    if (col == (row & ~3u)) {  // this thread holds the diagonal element
      const uint sel = row & 3u;
      Qd[row] = sel == 0u ? q0 : sel == 1u ? q1 : sel == 2u ? q2 : q3;
    }
  }
  const float s = blk_reduce(acc, red);
  if (t == 0) R[row] = frcp(s);
  if (row < 32u) Cs0[row * 256u + t] = 0.f;  // zero Cs0 for colmv_0
  if (row == 0 && t == 0) *out = 0.f;        // d_out poisoned 0xAA each call
}

// ---- colmv: dst[j] += sum_{128 rows} Q[i,j]*R[i]; also zero the other buf ---
__global__ __launch_bounds__(256) void k_colmv(const uint* __restrict__ Qw,
                                               const float* __restrict__ R,
                                               float* __restrict__ dst,
                                               float* __restrict__ zero_other) {
  const uint t = threadIdx.x;
  const uint col = blockIdx.x * 1024u + t * 4u;
  const uint row0 = blockIdx.y * 128u;
  if (blockIdx.y == 0u) {  // no other block touches zero_other this kernel
    float4 z; z.x = z.y = z.z = z.w = 0.f;
    *(float4*)(zero_other + col) = z;
  }
  float a0 = 0.f, a1 = 0.f, a2 = 0.f, a3 = 0.f;
  const uint* qp = Qw + (((size_t)row0 * NN + col) >> 2);
#pragma unroll 4
  for (uint rr = 0; rr < 128u; ++rr) {
    const float Rr = R[row0 + rr];  // block-uniform -> s_load
    float f0, f1, f2, f3;
    unpk4(qp[rr * 2048u], f0, f1, f2, f3);
    a0 = fmaf(f0, Rr, a0);
    a1 = fmaf(f1, Rr, a1);
    a2 = fmaf(f2, Rr, a2);
    a3 = fmaf(f3, Rr, a3);
  }
  atomicAdd(dst + col + 0, a0);  // 64 contributions/column -> low contention
  atomicAdd(dst + col + 1, a1);
  atomicAdd(dst + col + 2, a2);
  atomicAdd(dst + col + 3, a3);
}

// ---- rowmv: R[i] = 1/sum_j Q[i,j]*rcp(Csum[j]); 8 rows/block ----------------
__global__ __launch_bounds__(256) void k_rowmv(const uint* __restrict__ Qw,
                                               const float* __restrict__ Csrc,
                                               float* __restrict__ R) {
  __shared__ float ldsC[NN];
  __shared__ float red[4];
  const uint t = threadIdx.x;
  for (uint c = t * 4u; c < NN; c += 1024u) {
    const float4 s = *(const float4*)(Csrc + c);
    float4 o;
    o.x = frcp(s.x); o.y = frcp(s.y); o.z = frcp(s.z); o.w = frcp(s.w);
    *(float4*)(ldsC + c) = o;
  }
  __syncthreads();
#pragma unroll
  for (uint r = 0; r < 8u; ++r) {
    const uint row = blockIdx.x * 8u + r;
    float acc = 0.f;
#pragma unroll
    for (uint ch = 0; ch < 2u; ++ch) {
      const uint col = ch * 4096u + t * 16u;
      const float4 c0 = *(const float4*)(ldsC + col);
      const float4 c1 = *(const float4*)(ldsC + col + 4);
      const float4 c2 = *(const float4*)(ldsC + col + 8);
      const float4 c3 = *(const float4*)(ldsC + col + 12);
      const uint4 q = *(const uint4*)(Qw + (size_t)row * 2048u + (col >> 2));
      float a0, a1, a2, a3, b0, b1, b2, b3;
      unpk4(q.x, a0, a1, a2, a3);
      unpk4(q.y, b0, b1, b2, b3);
      acc += a0 * c0.x + a1 * c0.y + a2 * c0.z + a3 * c0.w;
      acc += b0 * c1.x + b1 * c1.y + b2 * c1.z + b3 * c1.w;
      unpk4(q.z, a0, a1, a2, a3);
      unpk4(q.w, b0, b1, b2, b3);
      acc += a0 * c2.x + a1 * c2.y + a2 * c2.z + a3 * c2.w;
      acc += b0 * c3.x + b1 * c3.y + b2 * c3.z + b3 * c3.w;
    }
    const float s = blk_reduce(acc, red);
    if (t == 0) R[row] = frcp(s);
  }
}

// ---- loss: sum_{i!=j} max(P-d[j]+m,0)+max(P-d[i]+m,0) -----------------------
__global__ __launch_bounds__(256) void k_loss(const uint* __restrict__ Qw,
                                              const float* __restrict__ R,
                                              const float* __restrict__ Cs,
                                              const float* __restrict__ Qd,
                                              float* __restrict__ out) {
  __shared__ float red[4];
  const uint t = threadIdx.x;
  const uint col = blockIdx.x * 1024u + t * 4u;
  const uint row0 = blockIdx.y * 128u;
  const float4 cs4 = *(const float4*)(Cs + col);
  const float4 r4 = *(const float4*)(R + col);
  const float4 qd4 = *(const float4*)(Qd + col);
  const float ci0 = frcp(cs4.x), ci1 = frcp(cs4.y), ci2 = frcp(cs4.z),
              ci3 = frcp(cs4.w);
  const float d0 = qd4.x * r4.x * ci0;
  const float d1 = qd4.y * r4.y * ci1;
  const float d2 = qd4.z * r4.z * ci2;
  const float d3 = qd4.w * r4.w * ci3;
  float acc = 0.f;
  const uint* qp = Qw + (((size_t)row0 * NN + col) >> 2);
  for (uint rr = 0; rr < 128u; ++rr) {
    const uint row = row0 + rr;
    const float Rr = R[row];                       // uniform -> s_load
    const float dr = Qd[row] * Rr * frcp(Cs[row]); // uniform scalars
    float f0, f1, f2, f3;
    unpk4(qp[rr * 2048u], f0, f1, f2, f3);
    float p, h;
    p = f0 * Rr * ci0;
    h = fmaxf(p - d0 + MARGIN, 0.f) + fmaxf(p - dr + MARGIN, 0.f);
    acc += (row == col + 0u) ? 0.f : h;
    p = f1 * Rr * ci1;
    h = fmaxf(p - d1 + MARGIN, 0.f) + fmaxf(p - dr + MARGIN, 0.f);
    acc += (row == col + 1u) ? 0.f : h;
    p = f2 * Rr * ci2;
    h = fmaxf(p - d2 + MARGIN, 0.f) + fmaxf(p - dr + MARGIN, 0.f);
    acc += (row == col + 2u) ? 0.f : h;
    p = f3 * Rr * ci3;
    h = fmaxf(p - d3 + MARGIN, 0.f) + fmaxf(p - dr + MARGIN, 0.f);
    acc += (row == col + 3u) ? 0.f : h;
  }
  const float s = blk_reduce(acc, red);
  if (t == 0) atomicAdd(out, s);
}

extern "C" void kernel_launch(void* const* d_in, const int* in_sizes, int n_in,
                              void* d_out, int out_size, void* d_ws,
                              size_t ws_size, hipStream_t stream) {
  const float* sims = (const float*)d_in[0];
  float* out = (float*)d_out;
  uint* Qw = (uint*)d_ws;                                   // 64 MB fp8 Q
  float* fb = (float*)((char*)d_ws + (size_t)NN * NN);
  float* R = fb;
  float* Cs[2] = {fb + NN, fb + 2 * NN};
  float* Qd = fb + 3 * NN;

  k_pass0<<<8192, 256, 0, stream>>>(sims, Qw, R, Qd, Cs[0], out);
  for (int k = 0; k < 5; ++k) {
    // dst = Cs[k&1]; zero the other buffer (last read by rowmv_{k-1})
    k_colmv<<<dim3(8, 64), 256, 0, stream>>>(Qw, R, Cs[k & 1], Cs[(k + 1) & 1]);
    if (k < 4) k_rowmv<<<1024, 256, 0, stream>>>(Qw, Cs[k & 1], R);
  }
  k_loss<<<dim3(8, 64), 256, 0, stream>>>(Qw, R, Cs[0], Qd, out);
}